// Round 1
// 219.322 us; speedup vs baseline: 1.1022x; 1.1022x over previous
//
#include <hip/hip_runtime.h>

#define N_NODES 100000
#define N_EDGES 1600000
#define D_IN 128
#define D_HID 64
#define BN_EPS 1e-5f

#define BUCKET_SHIFT 7
#define BUCKET_W 128                                    // nodes per bucket
#define N_BUCKETS ((N_NODES + BUCKET_W - 1) / BUCKET_W) // 782
#define N_BIN_BLOCKS 256
#define EDGES_PER_BLOCK (N_EDGES / N_BIN_BLOCKS)        // 6250 exact
#define GT 2                                            // gemm tiles per block

typedef __attribute__((ext_vector_type(8))) short bf16x8;
typedef __attribute__((ext_vector_type(4))) float f32x4;
typedef __attribute__((ext_vector_type(2))) _Float16 f16x2;
typedef __attribute__((ext_vector_type(4))) _Float16 f16x4;

__device__ __forceinline__ ushort f2bf(float f) {       // RTNE fp32 -> bf16
    unsigned u = __float_as_uint(f);
    u += 0x7FFF + ((u >> 16) & 1);
    return (ushort)(u >> 16);
}

// --- 1. per-bucket edge counts; persist per-block histograms ---
__global__ __launch_bounds__(256) void bin_count_kernel(const int* __restrict__ col,
                                                        int* __restrict__ bcount,
                                                        int* __restrict__ bhist) {
    __shared__ int hist[N_BUCKETS];
    const int t = threadIdx.x;
    for (int i = t; i < N_BUCKETS; i += 256) hist[i] = 0;
    __syncthreads();
    const int e0 = blockIdx.x * EDGES_PER_BLOCK;
    for (int j = t; j < EDGES_PER_BLOCK; j += 256)
        atomicAdd(&hist[col[e0 + j] >> BUCKET_SHIFT], 1);
    __syncthreads();
    for (int i = t; i < N_BUCKETS; i += 256) {
        int h = hist[i];
        bhist[blockIdx.x * N_BUCKETS + i] = h;
        if (h) atomicAdd(&bcount[i], h);
    }
}

// --- 2. exclusive scan of bucket counts (single block); init cursor ---
__global__ __launch_bounds__(1024) void scan_buckets_kernel(const int* __restrict__ bcount,
                                                            int* __restrict__ bstart,
                                                            int* __restrict__ bcursor,
                                                            int* __restrict__ row_start) {
    __shared__ int tmp[1024];
    int t = threadIdx.x;
    int val = (t < N_BUCKETS) ? bcount[t] : 0;
    tmp[t] = val;
    for (int off = 1; off < 1024; off <<= 1) {
        __syncthreads();
        int add = (t >= off) ? tmp[t - off] : 0;
        __syncthreads();
        tmp[t] += add;
    }
    __syncthreads();
    if (t < N_BUCKETS) {
        int s = tmp[t] - val;
        bstart[t] = s;
        bcursor[t] = s;
    }
    if (t == N_BUCKETS - 1) {
        bstart[N_BUCKETS] = tmp[t];
        row_start[N_NODES] = tmp[t];   // CSR sentinel
    }
}

// --- 3. scatter edges into bucket-grouped array, packed (cl<<17)|row ---
__global__ __launch_bounds__(256) void bin_scatter_kernel(const int* __restrict__ row,
                                                          const int* __restrict__ col,
                                                          const int* __restrict__ bhist,
                                                          int* __restrict__ bcursor,
                                                          int* __restrict__ binned) {
    __shared__ int hist[N_BUCKETS];
    __shared__ int lbase[N_BUCKETS];
    const int t = threadIdx.x;
    for (int i = t; i < N_BUCKETS; i += 256) {
        int h = bhist[blockIdx.x * N_BUCKETS + i];
        lbase[i] = h ? atomicAdd(&bcursor[i], h) : 0;
        hist[i] = 0;   // local rank cursor
    }
    __syncthreads();
    const int e0 = blockIdx.x * EDGES_PER_BLOCK;
    for (int j = t; j < EDGES_PER_BLOCK; j += 256) {
        int c = col[e0 + j];
        int r = row[e0 + j];
        int b = c >> BUCKET_SHIFT;
        int rank = atomicAdd(&hist[b], 1);
        binned[lbase[b] + rank] = ((c & (BUCKET_W - 1)) << 17) | r;
    }
}

// --- 4. bucket-local counting sort -> CSR + row_start + dinv (no global atomics) ---
__global__ __launch_bounds__(256) void bucket_csr_kernel(const int* __restrict__ binned,
                                                         const int* __restrict__ bstart,
                                                         int* __restrict__ csr_src,
                                                         int* __restrict__ row_start,
                                                         float* __restrict__ dinv) {
    __shared__ int hist[BUCKET_W];
    __shared__ int cursor[BUCKET_W];
    const int b = blockIdx.x;
    const int t = threadIdx.x;
    if (t < BUCKET_W) hist[t] = 0;
    __syncthreads();
    const int s = bstart[b], e = bstart[b + 1];
    for (int i = s + t; i < e; i += 256)
        atomicAdd(&hist[binned[i] >> 17], 1);
    __syncthreads();
    if (t < BUCKET_W) cursor[t] = hist[t];
    for (int off = 1; off < BUCKET_W; off <<= 1) {
        __syncthreads();
        int add = (t >= off && t < BUCKET_W) ? cursor[t - off] : 0;
        __syncthreads();
        if (t < BUCKET_W) cursor[t] += add;
    }
    __syncthreads();
    int excl = (t < BUCKET_W) ? (cursor[t] - hist[t]) : 0;
    __syncthreads();
    if (t < BUCKET_W) cursor[t] = excl;
    const int node = b * BUCKET_W + t;
    if (t < BUCKET_W && node < N_NODES) {
        row_start[node] = s + excl;
        dinv[node] = rsqrtf(1.0f + (float)hist[t]);
    }
    __syncthreads();
    for (int i = s + t; i < e; i += 256) {
        int p = binned[i];
        int pos = atomicAdd(&cursor[p >> 17], 1);
        csr_src[s + pos] = p & 0x1FFFF;
    }
}

// --- 5. MFMA gemm: h_s(f16) = dinv[n] * (x @ W1) ---
__global__ __launch_bounds__(256) void gemm_mfma_kernel(const float* __restrict__ x,
                                                        const float* __restrict__ W,
                                                        const float* __restrict__ dinv,
                                                        ushort* __restrict__ h_s) {
    __shared__ ushort xb[16 * 136];
    const int t = threadIdx.x;
    const int l = t & 63;
    const int wv = t >> 6;
    const int q = l >> 4;       // quad
    const int m = l & 15;
    bf16x8 bf[4];               // B[k=32s+8q+j][n=16wv+m]
    {
        const int n = wv * 16 + m;
        #pragma unroll
        for (int s = 0; s < 4; ++s)
            #pragma unroll
            for (int j = 0; j < 8; ++j)
                bf[s][j] = (short)f2bf(W[(32 * s + 8 * q + j) * D_HID + n]);
    }
    for (int tile = 0; tile < GT; ++tile) {
        const int node0 = blockIdx.x * (16 * GT) + tile * 16;
        __syncthreads();
        for (int i = t; i < 512; i += 256) {             // 16 rows x 32 float4
            int r = i >> 5, c4 = i & 31;
            float4 v = *(const float4*)&x[(size_t)(node0 + r) * D_IN + c4 * 4];
            ushort4 u = make_ushort4(f2bf(v.x), f2bf(v.y), f2bf(v.z), f2bf(v.w));
            *(ushort4*)&xb[r * 136 + c4 * 4] = u;
        }
        __syncthreads();
        f32x4 acc = {0.f, 0.f, 0.f, 0.f};
        #pragma unroll
        for (int s = 0; s < 4; ++s) {
            bf16x8 af = *(const bf16x8*)&xb[m * 136 + 32 * s + 8 * q];
            acc = __builtin_amdgcn_mfma_f32_16x16x32_bf16(af, bf[s], acc, 0, 0, 0);
        }
        #pragma unroll
        for (int r = 0; r < 4; ++r) {
            int node = node0 + q * 4 + r;    // C/D: row=(lane>>4)*4+reg, col=lane&15
            _Float16 hv = (_Float16)(acc[r] * dinv[node]);
            h_s[node * D_HID + wv * 16 + m] = __builtin_bit_cast(unsigned short, hv);
        }
    }
}

// --- 6. fused aggregate + bias/BN/relu + fc projection ---
// 4 nodes per wave: one 16-lane quarter per node, f16x4 (8B) per lane =
// 64 features per quarter. 4x gather work per wave lifetime amortizes the
// serial row_start->index->gather chain and the epilogue; VMEM instr count
// per byte halves vs f16x2. Degree divergence across quarters is handled
// by exec-masking (no predication VALU).
__global__ __launch_bounds__(256) void aggregate_kernel(const ushort* __restrict__ h_s,
                                                        const float* __restrict__ dinv,
                                                        const int* __restrict__ row_start,
                                                        const int* __restrict__ csr_src,
                                                        const float* __restrict__ b1,
                                                        const float* __restrict__ gamma,
                                                        const float* __restrict__ beta,
                                                        const float* __restrict__ mean,
                                                        const float* __restrict__ var,
                                                        const float* __restrict__ Wfc,
                                                        float4* __restrict__ uv) {
    const f16x4* __restrict__ hsv = (const f16x4*)h_s;   // [node][16] quads
    const int wvid = (blockIdx.x * 256 + threadIdx.x) >> 6; // wave id (grid exact)
    const int lane = threadIdx.x & 63;
    const int q = lane >> 4;                             // quarter 0..3
    const int ql = lane & 15;                            // feature quad 0..15
    const int n = wvid * 4 + q;                          // node
    f16x4 acc = hsv[n * 16 + ql];                        // self-loop (pre-scaled)
    const int start = row_start[n];
    const int cnt = row_start[n + 1] - start;
    int j = 0;
    for (; j + 8 <= cnt; j += 8) {                       // 8 gathers in flight/quarter
        int i0 = csr_src[start + j + 0];
        int i1 = csr_src[start + j + 1];
        int i2 = csr_src[start + j + 2];
        int i3 = csr_src[start + j + 3];
        int i4 = csr_src[start + j + 4];
        int i5 = csr_src[start + j + 5];
        int i6 = csr_src[start + j + 6];
        int i7 = csr_src[start + j + 7];
        f16x4 v0 = hsv[i0 * 16 + ql];
        f16x4 v1 = hsv[i1 * 16 + ql];
        f16x4 v2 = hsv[i2 * 16 + ql];
        f16x4 v3 = hsv[i3 * 16 + ql];
        f16x4 v4 = hsv[i4 * 16 + ql];
        f16x4 v5 = hsv[i5 * 16 + ql];
        f16x4 v6 = hsv[i6 * 16 + ql];
        f16x4 v7 = hsv[i7 * 16 + ql];
        acc += v0; acc += v1; acc += v2; acc += v3;
        acc += v4; acc += v5; acc += v6; acc += v7;
    }
    for (; j + 4 <= cnt; j += 4) {
        int i0 = csr_src[start + j + 0];
        int i1 = csr_src[start + j + 1];
        int i2 = csr_src[start + j + 2];
        int i3 = csr_src[start + j + 3];
        f16x4 v0 = hsv[i0 * 16 + ql];
        f16x4 v1 = hsv[i1 * 16 + ql];
        f16x4 v2 = hsv[i2 * 16 + ql];
        f16x4 v3 = hsv[i3 * 16 + ql];
        acc += v0; acc += v1; acc += v2; acc += v3;
    }
    for (; j + 2 <= cnt; j += 2) {
        int i0 = csr_src[start + j + 0];
        int i1 = csr_src[start + j + 1];
        f16x4 v0 = hsv[i0 * 16 + ql];
        f16x4 v1 = hsv[i1 * 16 + ql];
        acc += v0; acc += v1;
    }
    if (j < cnt)
        acc += hsv[csr_src[start + j] * 16 + ql];
    const float dn = dinv[n];
    float v0 = (float)acc.x * dn;
    float v1 = (float)acc.y * dn;
    float v2 = (float)acc.z * dn;
    float v3 = (float)acc.w * dn;
    float4 bb = *(const float4*)&b1[4 * ql];
    float4 mu = *(const float4*)&mean[4 * ql];
    float4 vr = *(const float4*)&var[4 * ql];
    float4 gm = *(const float4*)&gamma[4 * ql];
    float4 bt = *(const float4*)&beta[4 * ql];
    v0 = fmaxf(v0 + bb.x, 0.f);
    v1 = fmaxf(v1 + bb.y, 0.f);
    v2 = fmaxf(v2 + bb.z, 0.f);
    v3 = fmaxf(v3 + bb.w, 0.f);
    v0 = fmaxf((v0 - mu.x) * rsqrtf(vr.x + BN_EPS) * gm.x + bt.x, 0.f);
    v1 = fmaxf((v1 - mu.y) * rsqrtf(vr.y + BN_EPS) * gm.y + bt.y, 0.f);
    v2 = fmaxf((v2 - mu.z) * rsqrtf(vr.z + BN_EPS) * gm.z + bt.z, 0.f);
    v3 = fmaxf((v3 - mu.w) * rsqrtf(vr.w + BN_EPS) * gm.w + bt.w, 0.f);
    // Wfc[128][2]: rows 4ql..4ql+3 (top half) and 64+4ql..64+4ql+3 (bottom)
    float4 wA = *(const float4*)&Wfc[8 * ql];            // rows 4ql, 4ql+1
    float4 wB = *(const float4*)&Wfc[8 * ql + 4];        // rows 4ql+2, 4ql+3
    float4 wC = *(const float4*)&Wfc[128 + 8 * ql];      // rows 64+4ql, 64+4ql+1
    float4 wD = *(const float4*)&Wfc[128 + 8 * ql + 4];  // rows 64+4ql+2, 64+4ql+3
    float p0 = v0 * wA.x + v1 * wA.z + v2 * wB.x + v3 * wB.z;
    float p1 = v0 * wA.y + v1 * wA.w + v2 * wB.y + v3 * wB.w;
    float p2 = v0 * wC.x + v1 * wC.z + v2 * wD.x + v3 * wD.z;
    float p3 = v0 * wC.y + v1 * wC.w + v2 * wD.y + v3 * wD.w;
    #pragma unroll
    for (int off = 8; off > 0; off >>= 1) {              // reduce within quarter
        p0 += __shfl_xor(p0, off, 64);
        p1 += __shfl_xor(p1, off, 64);
        p2 += __shfl_xor(p2, off, 64);
        p3 += __shfl_xor(p3, off, 64);
    }
    if (ql == 0) uv[n] = make_float4(p0, p1, p2, p3);
}

// --- 7. edge head: 2 edges/thread; out = uv[row].xy + uv[col].zw + bfc ---
__global__ __launch_bounds__(256) void edgeout_kernel(const int* __restrict__ row,
                                                      const int* __restrict__ col,
                                                      const float4* __restrict__ uv,
                                                      const float* __restrict__ bfc,
                                                      float2* __restrict__ out) {
    int i = blockIdx.x * 256 + threadIdx.x;          // over N_EDGES/2 (grid exact)
    int e = i * 2;
    int2 rr = *(const int2*)&row[e];
    int2 cc = *(const int2*)&col[e];
    float4 a0 = uv[rr.x];
    float4 b0 = uv[cc.x];
    float4 a1 = uv[rr.y];
    float4 b1 = uv[cc.y];
    float c0 = bfc[0], c1 = bfc[1];
    float4 o = make_float4(a0.x + b0.z + c0, a0.y + b0.w + c1,
                           a1.x + b1.z + c0, a1.y + b1.w + c1);
    *(float4*)&out[e] = o;
}

extern "C" void kernel_launch(void* const* d_in, const int* in_sizes, int n_in,
                              void* d_out, int out_size, void* d_ws, size_t ws_size,
                              hipStream_t stream) {
    const float* x     = (const float*)d_in[0];
    const int*   ei    = (const int*)d_in[1];
    const int*   row   = ei;             // sources
    const int*   col   = ei + N_EDGES;   // targets
    const float* W1    = (const float*)d_in[2];
    const float* b1    = (const float*)d_in[3];
    const float* gamma = (const float*)d_in[4];
    const float* beta  = (const float*)d_in[5];
    const float* mean  = (const float*)d_in[6];
    const float* var   = (const float*)d_in[7];
    const float* Wfc   = (const float*)d_in[8];
    const float* bfc   = (const float*)d_in[9];
    float2* out = (float2*)d_out;

    char* ws = (char*)d_ws;
    size_t off = 0;
    ushort* h_s      = (ushort*)(ws + off); off += (size_t)N_NODES * D_HID * 2; // 12.8 MB
    int*   binned    = (int*)(ws + off);    off += (size_t)N_EDGES * 4;         // 6.4 MB
    int*   csr_src   = (int*)(ws + off);    off += (size_t)N_EDGES * 4;         // 6.4 MB
    int*   bhist     = (int*)(ws + off);    off += (size_t)N_BIN_BLOCKS * N_BUCKETS * 4; // 0.8 MB
    int*   bcount    = (int*)(ws + off);    off += (size_t)(N_BUCKETS + 2) * 4;
    int*   bstart    = (int*)(ws + off);    off += (size_t)(N_BUCKETS + 2) * 4;
    int*   bcursor   = (int*)(ws + off);    off += (size_t)(N_BUCKETS + 2) * 4;
    int*   row_start = (int*)(ws + off);    off += (size_t)(N_NODES + 4) * 4;
    float* dinv      = (float*)(ws + off);  off += (size_t)N_NODES * 4;
    float4* uv       = (float4*)(ws + off); off += (size_t)N_NODES * 16;        // 1.6 MB

    hipMemsetAsync(bcount, 0, (N_BUCKETS + 1) * sizeof(int), stream);
    bin_count_kernel<<<N_BIN_BLOCKS, 256, 0, stream>>>(col, bcount, bhist);
    scan_buckets_kernel<<<1, 1024, 0, stream>>>(bcount, bstart, bcursor, row_start);
    bin_scatter_kernel<<<N_BIN_BLOCKS, 256, 0, stream>>>(row, col, bhist, bcursor, binned);
    bucket_csr_kernel<<<N_BUCKETS, 256, 0, stream>>>(binned, bstart, csr_src, row_start, dinv);
    gemm_mfma_kernel<<<N_NODES / (16 * GT), 256, 0, stream>>>(x, W1, dinv, h_s);
    aggregate_kernel<<<N_NODES / 16, 256, 0, stream>>>(h_s, dinv, row_start, csr_src,
                                                       b1, gamma, beta, mean, var,
                                                       Wfc, uv);
    edgeout_kernel<<<N_EDGES / 512, 256, 0, stream>>>(row, col, uv, bfc, out);
}

// Round 2
// 203.677 us; speedup vs baseline: 1.1868x; 1.0768x over previous
//
#include <hip/hip_runtime.h>

#define N_NODES 100000
#define N_EDGES 1600000
#define D_IN 128
#define D_HID 64
#define BN_EPS 1e-5f

#define BUCKET_SHIFT 7
#define BUCKET_W 128                                    // nodes per bucket
#define N_BUCKETS ((N_NODES + BUCKET_W - 1) / BUCKET_W) // 782
#define BCAP 4096                                       // fixed per-bucket capacity (mean 2046, sigma 45)
#define N_BIN_BLOCKS 256
#define EDGES_PER_BLOCK (N_EDGES / N_BIN_BLOCKS)        // 6250 exact
#define GT 2                                            // gemm tiles per block

typedef __attribute__((ext_vector_type(8))) short bf16x8;
typedef __attribute__((ext_vector_type(4))) float f32x4;
typedef __attribute__((ext_vector_type(8))) _Float16 f16x8;

__device__ __forceinline__ ushort f2bf(float f) {       // RTNE fp32 -> bf16
    unsigned u = __float_as_uint(f);
    u += 0x7FFF + ((u >> 16) & 1);
    return (ushort)(u >> 16);
}

// --- 1. fused bin: per-block LDS count -> reserve via global atomic -> scatter ---
// Fixed-capacity bucket regions (b*BCAP) eliminate bin_count + scan kernels.
__global__ __launch_bounds__(256) void bin_scatter_kernel(const int* __restrict__ row,
                                                          const int* __restrict__ col,
                                                          int* __restrict__ bcursor,
                                                          int* __restrict__ binned) {
    __shared__ int hist[N_BUCKETS];
    __shared__ int lbase[N_BUCKETS];
    const int t = threadIdx.x;
    for (int i = t; i < N_BUCKETS; i += 256) hist[i] = 0;
    __syncthreads();
    const int e0 = blockIdx.x * EDGES_PER_BLOCK;
    for (int j = t; j < EDGES_PER_BLOCK; j += 256)
        atomicAdd(&hist[col[e0 + j] >> BUCKET_SHIFT], 1);
    __syncthreads();
    for (int i = t; i < N_BUCKETS; i += 256) {
        int h = hist[i];
        lbase[i] = h ? (i * BCAP + atomicAdd(&bcursor[i], h)) : 0;
        hist[i] = 0;   // local rank cursor
    }
    __syncthreads();
    for (int j = t; j < EDGES_PER_BLOCK; j += 256) {     // col re-read is L2-hot
        int c = col[e0 + j];
        int r = row[e0 + j];
        int b = c >> BUCKET_SHIFT;
        int rank = atomicAdd(&hist[b], 1);
        binned[lbase[b] + rank] = ((c & (BUCKET_W - 1)) << 17) | r;
    }
}

// --- 2. bucket-local counting sort -> CSR + (start,cnt) + dinv ---
__global__ __launch_bounds__(256) void bucket_csr_kernel(const int* __restrict__ binned,
                                                         const int* __restrict__ bcursor,
                                                         int* __restrict__ csr_src,
                                                         int2* __restrict__ rs2,
                                                         float* __restrict__ dinv) {
    __shared__ int hist[BUCKET_W];
    __shared__ int cursor[BUCKET_W];
    const int b = blockIdx.x;
    const int t = threadIdx.x;
    if (t < BUCKET_W) hist[t] = 0;
    __syncthreads();
    const int s = b * BCAP;
    const int e = s + bcursor[b];
    for (int i = s + t; i < e; i += 256)
        atomicAdd(&hist[binned[i] >> 17], 1);
    __syncthreads();
    if (t < BUCKET_W) cursor[t] = hist[t];
    for (int off = 1; off < BUCKET_W; off <<= 1) {
        __syncthreads();
        int add = (t >= off && t < BUCKET_W) ? cursor[t - off] : 0;
        __syncthreads();
        if (t < BUCKET_W) cursor[t] += add;
    }
    __syncthreads();
    int excl = (t < BUCKET_W) ? (cursor[t] - hist[t]) : 0;
    __syncthreads();
    if (t < BUCKET_W) cursor[t] = excl;
    const int node = b * BUCKET_W + t;
    if (t < BUCKET_W && node < N_NODES) {
        rs2[node] = make_int2(s + excl, hist[t]);
        dinv[node] = rsqrtf(1.0f + (float)hist[t]);
    }
    __syncthreads();
    for (int i = s + t; i < e; i += 256) {
        int p = binned[i];
        int pos = atomicAdd(&cursor[p >> 17], 1);
        csr_src[s + pos] = p & 0x1FFFF;
    }
}

// --- 3. MFMA gemm: h_s(f16) = dinv[n] * (x @ W1) ---
__global__ __launch_bounds__(256) void gemm_mfma_kernel(const float* __restrict__ x,
                                                        const float* __restrict__ W,
                                                        const float* __restrict__ dinv,
                                                        ushort* __restrict__ h_s) {
    __shared__ ushort xb[16 * 136];
    const int t = threadIdx.x;
    const int l = t & 63;
    const int wv = t >> 6;
    const int q = l >> 4;       // quad
    const int m = l & 15;
    bf16x8 bf[4];               // B[k=32s+8q+j][n=16wv+m]
    {
        const int n = wv * 16 + m;
        #pragma unroll
        for (int s = 0; s < 4; ++s)
            #pragma unroll
            for (int j = 0; j < 8; ++j)
                bf[s][j] = (short)f2bf(W[(32 * s + 8 * q + j) * D_HID + n]);
    }
    for (int tile = 0; tile < GT; ++tile) {
        const int node0 = blockIdx.x * (16 * GT) + tile * 16;
        __syncthreads();
        for (int i = t; i < 512; i += 256) {             // 16 rows x 32 float4
            int r = i >> 5, c4 = i & 31;
            float4 v = *(const float4*)&x[(size_t)(node0 + r) * D_IN + c4 * 4];
            ushort4 u = make_ushort4(f2bf(v.x), f2bf(v.y), f2bf(v.z), f2bf(v.w));
            *(ushort4*)&xb[r * 136 + c4 * 4] = u;
        }
        __syncthreads();
        f32x4 acc = {0.f, 0.f, 0.f, 0.f};
        #pragma unroll
        for (int s = 0; s < 4; ++s) {
            bf16x8 af = *(const bf16x8*)&xb[m * 136 + 32 * s + 8 * q];
            acc = __builtin_amdgcn_mfma_f32_16x16x32_bf16(af, bf[s], acc, 0, 0, 0);
        }
        #pragma unroll
        for (int r = 0; r < 4; ++r) {
            int node = node0 + q * 4 + r;    // C/D: row=(lane>>4)*4+reg, col=lane&15
            _Float16 hv = (_Float16)(acc[r] * dinv[node]);
            h_s[node * D_HID + wv * 16 + m] = __builtin_bit_cast(unsigned short, hv);
        }
    }
}

// --- 4. fused aggregate + bias/BN/relu + fc projection ---
// 8 nodes per wave: one 8-lane octet per node, f16x8 (16B) per lane =
// one full 128B node line per gather group. Amortizes the serial
// row_start->index->gather chain and epilogue over 8 nodes; halves VMEM
// instruction count per gathered byte vs f16x4.
__global__ __launch_bounds__(256) void aggregate_kernel(const ushort* __restrict__ h_s,
                                                        const float* __restrict__ dinv,
                                                        const int2* __restrict__ rs2,
                                                        const int* __restrict__ csr_src,
                                                        const float* __restrict__ b1,
                                                        const float* __restrict__ gamma,
                                                        const float* __restrict__ beta,
                                                        const float* __restrict__ mean,
                                                        const float* __restrict__ var,
                                                        const float* __restrict__ Wfc,
                                                        float4* __restrict__ uv) {
    const f16x8* __restrict__ hsv = (const f16x8*)h_s;   // [node][8] octets
    const int wvid = (blockIdx.x * 256 + threadIdx.x) >> 6; // wave id (grid exact)
    const int lane = threadIdx.x & 63;
    const int oct = lane >> 3;                           // node slot 0..7
    const int ol = lane & 7;                             // feature octet 0..7
    const int n = wvid * 8 + oct;                        // node
    f16x8 acc = hsv[n * 8 + ol];                         // self-loop (pre-scaled)
    const int2 rs = rs2[n];
    const int start = rs.x;
    const int cnt = rs.y;
    int j = 0;
    for (; j + 8 <= cnt; j += 8) {                       // 8 gathers in flight/octet
        int i0 = csr_src[start + j + 0];
        int i1 = csr_src[start + j + 1];
        int i2 = csr_src[start + j + 2];
        int i3 = csr_src[start + j + 3];
        int i4 = csr_src[start + j + 4];
        int i5 = csr_src[start + j + 5];
        int i6 = csr_src[start + j + 6];
        int i7 = csr_src[start + j + 7];
        f16x8 v0 = hsv[i0 * 8 + ol];
        f16x8 v1 = hsv[i1 * 8 + ol];
        f16x8 v2 = hsv[i2 * 8 + ol];
        f16x8 v3 = hsv[i3 * 8 + ol];
        f16x8 v4 = hsv[i4 * 8 + ol];
        f16x8 v5 = hsv[i5 * 8 + ol];
        f16x8 v6 = hsv[i6 * 8 + ol];
        f16x8 v7 = hsv[i7 * 8 + ol];
        acc += v0; acc += v1; acc += v2; acc += v3;
        acc += v4; acc += v5; acc += v6; acc += v7;
    }
    for (; j + 4 <= cnt; j += 4) {
        int i0 = csr_src[start + j + 0];
        int i1 = csr_src[start + j + 1];
        int i2 = csr_src[start + j + 2];
        int i3 = csr_src[start + j + 3];
        f16x8 v0 = hsv[i0 * 8 + ol];
        f16x8 v1 = hsv[i1 * 8 + ol];
        f16x8 v2 = hsv[i2 * 8 + ol];
        f16x8 v3 = hsv[i3 * 8 + ol];
        acc += v0; acc += v1; acc += v2; acc += v3;
    }
    for (; j + 2 <= cnt; j += 2) {
        int i0 = csr_src[start + j + 0];
        int i1 = csr_src[start + j + 1];
        f16x8 v0 = hsv[i0 * 8 + ol];
        f16x8 v1 = hsv[i1 * 8 + ol];
        acc += v0; acc += v1;
    }
    if (j < cnt)
        acc += hsv[csr_src[start + j] * 8 + ol];
    // epilogue: lane handles features f0..f0+7 of node n
    const float dn = dinv[n];
    const int f0 = 8 * ol;
    float a[8];
    #pragma unroll
    for (int k = 0; k < 8; ++k) a[k] = (float)acc[k] * dn;
    float bb[8], mu[8], vr[8], gm[8], bt[8];
    *(float4*)&bb[0] = *(const float4*)&b1[f0];    *(float4*)&bb[4] = *(const float4*)&b1[f0 + 4];
    *(float4*)&mu[0] = *(const float4*)&mean[f0];  *(float4*)&mu[4] = *(const float4*)&mean[f0 + 4];
    *(float4*)&vr[0] = *(const float4*)&var[f0];   *(float4*)&vr[4] = *(const float4*)&var[f0 + 4];
    *(float4*)&gm[0] = *(const float4*)&gamma[f0]; *(float4*)&gm[4] = *(const float4*)&gamma[f0 + 4];
    *(float4*)&bt[0] = *(const float4*)&beta[f0];  *(float4*)&bt[4] = *(const float4*)&beta[f0 + 4];
    #pragma unroll
    for (int k = 0; k < 8; ++k) {
        float v = fmaxf(a[k] + bb[k], 0.f);
        a[k] = fmaxf((v - mu[k]) * rsqrtf(vr[k] + BN_EPS) * gm[k] + bt[k], 0.f);
    }
    // Wfc[128][2]: top rows f0..f0+7 -> p0/p1; bottom rows 64+f0.. -> p2/p3
    float wt[16], wb[16];
    #pragma unroll
    for (int k = 0; k < 4; ++k) {
        *(float4*)&wt[4 * k] = *(const float4*)&Wfc[2 * f0 + 4 * k];
        *(float4*)&wb[4 * k] = *(const float4*)&Wfc[128 + 2 * f0 + 4 * k];
    }
    float p0 = 0.f, p1 = 0.f, p2 = 0.f, p3 = 0.f;
    #pragma unroll
    for (int k = 0; k < 8; ++k) {
        p0 += a[k] * wt[2 * k];
        p1 += a[k] * wt[2 * k + 1];
        p2 += a[k] * wb[2 * k];
        p3 += a[k] * wb[2 * k + 1];
    }
    #pragma unroll
    for (int off = 4; off > 0; off >>= 1) {              // reduce within octet
        p0 += __shfl_xor(p0, off, 64);
        p1 += __shfl_xor(p1, off, 64);
        p2 += __shfl_xor(p2, off, 64);
        p3 += __shfl_xor(p3, off, 64);
    }
    if (ol == 0) uv[n] = make_float4(p0, p1, p2, p3);
}

// --- 5. edge head: 2 edges/thread; out = uv[row].xy + uv[col].zw + bfc ---
__global__ __launch_bounds__(256) void edgeout_kernel(const int* __restrict__ row,
                                                      const int* __restrict__ col,
                                                      const float4* __restrict__ uv,
                                                      const float* __restrict__ bfc,
                                                      float2* __restrict__ out) {
    int i = blockIdx.x * 256 + threadIdx.x;          // over N_EDGES/2 (grid exact)
    int e = i * 2;
    int2 rr = *(const int2*)&row[e];
    int2 cc = *(const int2*)&col[e];
    float4 a0 = uv[rr.x];
    float4 b0 = uv[cc.x];
    float4 a1 = uv[rr.y];
    float4 b1 = uv[cc.y];
    float c0 = bfc[0], c1 = bfc[1];
    float4 o = make_float4(a0.x + b0.z + c0, a0.y + b0.w + c1,
                           a1.x + b1.z + c0, a1.y + b1.w + c1);
    *(float4*)&out[e] = o;
}

extern "C" void kernel_launch(void* const* d_in, const int* in_sizes, int n_in,
                              void* d_out, int out_size, void* d_ws, size_t ws_size,
                              hipStream_t stream) {
    const float* x     = (const float*)d_in[0];
    const int*   ei    = (const int*)d_in[1];
    const int*   row   = ei;             // sources
    const int*   col   = ei + N_EDGES;   // targets
    const float* W1    = (const float*)d_in[2];
    const float* b1    = (const float*)d_in[3];
    const float* gamma = (const float*)d_in[4];
    const float* beta  = (const float*)d_in[5];
    const float* mean  = (const float*)d_in[6];
    const float* var   = (const float*)d_in[7];
    const float* Wfc   = (const float*)d_in[8];
    const float* bfc   = (const float*)d_in[9];
    float2* out = (float2*)d_out;

    char* ws = (char*)d_ws;
    size_t off = 0;
    ushort* h_s      = (ushort*)(ws + off); off += (size_t)N_NODES * D_HID * 2;    // 12.8 MB
    int*   binned    = (int*)(ws + off);    off += (size_t)N_BUCKETS * BCAP * 4;   // 12.8 MB
    int*   csr_src   = (int*)(ws + off);    off += (size_t)N_BUCKETS * BCAP * 4;   // 12.8 MB
    int*   bcursor   = (int*)(ws + off);    off += ((size_t)N_BUCKETS * 4 + 15) & ~(size_t)15;
    int2*  rs2       = (int2*)(ws + off);   off += (size_t)N_NODES * 8;            // 0.8 MB
    float* dinv      = (float*)(ws + off);  off += (size_t)N_NODES * 4;
    float4* uv       = (float4*)(ws + off); off += (size_t)N_NODES * 16;           // 1.6 MB

    hipMemsetAsync(bcursor, 0, N_BUCKETS * sizeof(int), stream);
    bin_scatter_kernel<<<N_BIN_BLOCKS, 256, 0, stream>>>(row, col, bcursor, binned);
    bucket_csr_kernel<<<N_BUCKETS, 256, 0, stream>>>(binned, bcursor, csr_src, rs2, dinv);
    gemm_mfma_kernel<<<N_NODES / (16 * GT), 256, 0, stream>>>(x, W1, dinv, h_s);
    aggregate_kernel<<<N_NODES / 32, 256, 0, stream>>>(h_s, dinv, rs2, csr_src,
                                                       b1, gamma, beta, mean, var,
                                                       Wfc, uv);
    edgeout_kernel<<<N_EDGES / 512, 256, 0, stream>>>(row, col, uv, bfc, out);
}